// Round 19
// baseline (1126.538 us; speedup 1.0000x reference)
//
#include <hip/hip_runtime.h>
#include <stdint.h>

// Problem constants
#define NB 16
#define NN 4096
#define NS 1024
#define NK 32
#define INV_CNT (1.0f/524288.0f)   // 1/(B*S*K)
#define BN_EPS_ 1e-5f

// exact-rounding helpers (block FMA contraction to match numpy elementwise semantics)
__device__ __forceinline__ float frn_mul(float a,float b){ return __fmul_rn(a,b); }
__device__ __forceinline__ float frn_add(float a,float b){ return __fadd_rn(a,b); }
__device__ __forceinline__ float frn_sub(float a,float b){ return __fsub_rn(a,b); }

__device__ __forceinline__ unsigned long long ullmax_(unsigned long long a, unsigned long long b){ return a>b?a:b; }

typedef float v2f __attribute__((ext_vector_type(2)));

// u64 DPP shift/bcast: both halves use same ctrl => coherent source lane.
template<int CTRL>
__device__ __forceinline__ unsigned long long dpp_max_u64(unsigned long long v){
  int lo = __builtin_amdgcn_update_dpp((int)(unsigned)v, (int)(unsigned)v, CTRL, 0xf, 0xf, false);
  int hi = __builtin_amdgcn_update_dpp((int)(unsigned)(v>>32), (int)(unsigned)(v>>32), CTRL, 0xf, 0xf, false);
  unsigned long long o = (((unsigned long long)(unsigned)hi)<<32) | (unsigned long long)(unsigned)lo;
  return (o>v)?o:v;
}

// packed-FMA helper: 8 FMA as 4 v_pk_fma_f32 (contraction fuses per element,
// numerically identical to fmaf). Unpack of float4 into v2f pairs is pure
// register naming (adjacent VGPRs), no extra instructions.
__device__ __forceinline__ void pkfma8(v2f* acc, float4 lo, float4 hi, float w){
  v2f w2; w2.x=w; w2.y=w;
  v2f p0; p0.x=lo.x; p0.y=lo.y;
  v2f p1; p1.x=lo.z; p1.y=lo.w;
  v2f p2; p2.x=hi.x; p2.y=hi.y;
  v2f p3; p3.x=hi.z; p3.y=hi.w;
  acc[0] = p0*w2 + acc[0];
  acc[1] = p1*w2 + acc[1];
  acc[2] = p2*w2 + acc[2];
  acc[3] = p3*w2 + acc[3];
}

// ---------------------------------------------------------------------------
// FPS v7 (settled floor ~620-630us). Block 0 also zeroes stats[].
// ---------------------------------------------------------------------------
__global__ __launch_bounds__(256) void k_fps(const float* __restrict__ xyz,
                                             int* __restrict__ fpsIdx,
                                             float* __restrict__ norms,
                                             float* __restrict__ outNewXyz,
                                             float* __restrict__ stats){
  const int b = blockIdx.x;
  const float* bxp = xyz + (size_t)b*3*NN;
  const int t = threadIdx.x, lane = t&63, wv = t>>6;
  if (b==0){ stats[t]=0.f; stats[256+t]=0.f; }
  __shared__ __align__(16) float4 sxyz[NN];           // 64 KB
  __shared__ __align__(32) unsigned long long red[2][4];
  v2f px2[8], py2[8], pz2[8], dd2[8];
  #pragma unroll
  for(int j=0;j<8;j++){
    #pragma unroll
    for(int k=0;k<2;k++){
      int n = t + (2*j+k)*256;
      float x=bxp[n], y=bxp[NN+n], z=bxp[2*NN+n];
      if(k==0){ px2[j].x=x; py2[j].x=y; pz2[j].x=z; }
      else    { px2[j].y=x; py2[j].y=y; pz2[j].y=z; }
      float nr = frn_add(frn_add(frn_mul(x,x),frn_mul(y,y)),frn_mul(z,z));
      norms[(size_t)b*NN+n]=nr;
      sxyz[n] = make_float4(x,y,z,0.f);
    }
    dd2[j].x=1e10f; dd2[j].y=1e10f;
  }
  const int rnb = NN-1-t;
  __syncthreads();
  int cur = 0;
  for(int it=0; it<NS; ++it){
    float4 c = sxyz[cur];                              // broadcast LDS read
    if (t==0){
      fpsIdx[b*NS+it]=cur;
      outNewXyz[(size_t)b*3*NS + it]        = c.x;
      outNewXyz[(size_t)b*3*NS + NS + it]   = c.y;
      outNewXyz[(size_t)b*3*NS + 2*NS + it] = c.z;
    }
    float bestv = -1.0f; int bestr = 0;
    {
      #pragma clang fp contract(off)
      v2f cx2; cx2.x=c.x; cx2.y=c.x;
      v2f cy2; cy2.x=c.y; cy2.y=c.y;
      v2f cz2; cz2.x=c.z; cz2.y=c.z;
      #pragma unroll
      for(int j=0;j<8;j++){
        v2f dx = px2[j] - cx2;
        v2f dy = py2[j] - cy2;
        v2f dz = pz2[j] - cz2;
        v2f d  = ((dx*dx) + (dy*dy)) + (dz*dz);   // pk_mul/pk_add, RN, no FMA
        float nd0 = fminf(dd2[j].x, d.x);
        dd2[j].x = nd0;
        bool g0 = nd0 > bestv;    // ascending i + strict > => smallest n on tie
        bestv = g0?nd0:bestv; bestr = g0?(rnb-((2*j)<<8)):bestr;
        float nd1 = fminf(dd2[j].y, d.y);
        dd2[j].y = nd1;
        bool g1 = nd1 > bestv;
        bestv = g1?nd1:bestv; bestr = g1?(rnb-((2*j+1)<<8)):bestr;
      }
    }
    unsigned long long best = (((unsigned long long)__float_as_uint(bestv))<<32)
                            | (unsigned long long)(unsigned)bestr;
    best = dpp_max_u64<0x111>(best);
    best = dpp_max_u64<0x112>(best);
    best = dpp_max_u64<0x114>(best);
    best = dpp_max_u64<0x118>(best);
    best = dpp_max_u64<0x142>(best);
    best = dpp_max_u64<0x143>(best);
    if (lane==63) red[it&1][wv]=best;
    __syncthreads();
    unsigned long long v = ullmax_(ullmax_(red[it&1][0], red[it&1][1]),
                                   ullmax_(red[it&1][2], red[it&1][3]));
    cur = NN-1-(int)(unsigned)(v & 0xffffffffull);
    cur = __builtin_amdgcn_readfirstlane(cur);
  }
}

// ---------------------------------------------------------------------------
// Ball query + grouping (unchanged)
// ---------------------------------------------------------------------------
__global__ __launch_bounds__(256) void k_group(const float* __restrict__ xyz,
                                               const float* __restrict__ pts,
                                               const float* __restrict__ norms,
                                               const int* __restrict__ fpsIdx,
                                               float* __restrict__ grouped){
  const int t=threadIdx.x, lane=t&63, wv=t>>6;
  const int g = blockIdx.x*4 + wv;            // 0..16383
  const int b = g>>10, s = g&1023;
  const float* bx = xyz + (size_t)b*3*NN;
  const float* bp = pts + (size_t)b*3*NN;
  int ci = __builtin_amdgcn_readfirstlane(fpsIdx[b*NS+s]);
  float cx=bx[ci], cy=bx[NN+ci], cz=bx[2*NN+ci];
  float cn2 = norms[(size_t)b*NN+ci];
  __shared__ __align__(16) float stage[4][NK][8];
  int cnt=0;
  for(int ch=0; ch<NN/64; ++ch){
    if (cnt>=NK) break;
    int n = ch*64 + lane;
    float x=bx[n], y=bx[NN+n], z=bx[2*NN+n];
    float pn2 = norms[(size_t)b*NN+n];
    float dot = frn_add(frn_add(frn_mul(cx,x),frn_mul(cy,y)),frn_mul(cz,z));
    float sqr = frn_sub(frn_add(cn2,pn2), frn_mul(2.0f,dot));
    bool ok = !(sqr > 0.04f);                 // in-ball iff sqr <= R^2
    unsigned long long m = __ballot(ok);
    int pos = cnt + __popcll(m & ((1ull<<lane)-1ull));
    if (ok && pos<NK){
      float q0=bp[n], q1=bp[NN+n], q2=bp[2*NN+n];
      float* r = &stage[wv][pos][0];
      r[0]=frn_sub(x,cx); r[1]=frn_sub(y,cy); r[2]=frn_sub(z,cz);
      r[3]=q0; r[4]=q1; r[5]=q2; r[6]=0.f; r[7]=0.f;
    }
    cnt += __popcll(m);
  }
  __syncthreads();
  int c2 = cnt<NK?cnt:NK;
  if (lane>=c2 && lane<NK){
    #pragma unroll
    for(int j=0;j<8;j++) stage[wv][lane][j]=stage[wv][0][j];
  }
  __syncthreads();
  float4* dst = (float4*)(grouped + (size_t)g*NK*8);
  dst[lane] = ((const float4*)&stage[wv][0][0])[lane];
}

__device__ __forceinline__ void fma8(float* av, float4 lo, float4 hi, float w){
  av[0]=fmaf(lo.x,w,av[0]); av[1]=fmaf(lo.y,w,av[1]);
  av[2]=fmaf(lo.z,w,av[2]); av[3]=fmaf(lo.w,w,av[3]);
  av[4]=fmaf(hi.x,w,av[4]); av[5]=fmaf(hi.y,w,av[5]);
  av[6]=fmaf(hi.z,w,av[6]); av[7]=fmaf(hi.w,w,av[7]);
}

// ---------------------------------------------------------------------------
// MLP stage 1: conv1 -> stats[0..64)=sum, [64..128)=sq. (unchanged)
// ---------------------------------------------------------------------------
__global__ __launch_bounds__(256) void k_mlp1(const float* __restrict__ grouped,
    const float* __restrict__ w1c, const float* __restrict__ b1c,
    float* __restrict__ stats){
  const int t=threadIdx.x, lane=t&63, wv=t>>6;
  __shared__ float sAcc[128];
  __shared__ __align__(16) float h0L[4][8][12];
  for(int i=t;i<128;i+=256) sAcc[i]=0.f;
  float w1r[6];
  #pragma unroll
  for(int c=0;c<6;c++) w1r[c]=w1c[lane*6+c];
  float bias1=b1c[lane];
  __syncthreads();
  float sum0=0.f, sq0=0.f;
  const int rowBase = blockIdx.x*256 + wv*64;
  float* h0 = &h0L[wv][0][0];
  for(int bt=0; bt<8; ++bt){
    const int rb = rowBase + bt*8;
    h0[(lane&7)*12 + (lane>>3)] = grouped[(size_t)rb*8 + lane];
    __builtin_amdgcn_wave_barrier();
    float a1[8];
    #pragma unroll
    for(int r=0;r<8;r++) a1[r]=bias1;
    #pragma unroll
    for(int c=0;c<6;c++){
      float4 lo = *(const float4*)&h0[c*12+0];
      float4 hi = *(const float4*)&h0[c*12+4];
      fma8(a1, lo, hi, w1r[c]);
    }
    #pragma unroll
    for(int r=0;r<8;r++){ sum0+=a1[r]; sq0=fmaf(a1[r],a1[r],sq0); }
    __builtin_amdgcn_wave_barrier();
  }
  atomicAdd(&sAcc[lane], sum0); atomicAdd(&sAcc[64+lane], sq0);
  __syncthreads();
  for(int i=t;i<128;i+=256) atomicAdd(&stats[i], sAcc[i]);
}

// ---------------------------------------------------------------------------
// MLP stage 2: conv1,bn1,relu,conv2 -> stats[128..192)=sum,[192..256)=sq.
// STORE=1 additionally writes raw conv2 output to h2raw[row][64].
// NEW this round: conv2 inner loop uses v2f accumulators -> v_pk_fma_f32
// (2 FMA/instr, fused per element = numerically identical to fmaf; unpack
// order preserved => stats bit-identical).
// ---------------------------------------------------------------------------
template<int STORE>
__global__ __launch_bounds__(256) void k_mlp2(const float* __restrict__ grouped,
    const float* __restrict__ w1c,const float* __restrict__ b1c,
    const float* __restrict__ w2c,const float* __restrict__ b2c,
    const float* __restrict__ g1,const float* __restrict__ bb1,
    float* __restrict__ stats,
    float* __restrict__ h2raw){
  const int t=threadIdx.x, lane=t&63, wv=t>>6;
  const int h=lane>>5, li=lane&31, c0=li, c1=li+32, r8=h*8;
  __shared__ float sAcc[128];
  __shared__ __align__(16) float h0L[4][8][20];
  __shared__ __align__(16) float h1L[4][64][20];
  __shared__ __align__(8)  float2 ws2[64][32];   // [in c][li] = {w2[li][c], w2[li+32][c]}
  for(int i=t;i<128;i+=256) sAcc[i]=0.f;
  for(int i=t;i<2048;i+=256){
    int c=i>>5, l2=i&31;
    ws2[c][l2] = make_float2(w2c[l2*64+c], w2c[(l2+32)*64+c]);
  }

  float w1r0[6], w1r1[6];
  #pragma unroll
  for(int c=0;c<6;c++){ w1r0[c]=w1c[c0*6+c]; w1r1[c]=w1c[c1*6+c]; }
  float bias1a=b1c[c0], bias1b=b1c[c1];
  float mmA = stats[c0]*INV_CNT;
  float vvA = stats[64+c0]*INV_CNT - mmA*mmA;
  float A1a = g1[c0]*rsqrtf(vvA+BN_EPS_);
  float B1a = bb1[c0]-mmA*A1a;
  float mmB = stats[c1]*INV_CNT;
  float vvB = stats[64+c1]*INV_CNT - mmB*mmB;
  float A1b = g1[c1]*rsqrtf(vvB+BN_EPS_);
  float B1b = bb1[c1]-mmB*A1b;
  float bias2a=b2c[c0], bias2b=b2c[c1];
  __syncthreads();

  float sumA=0.f,sqA=0.f,sumB=0.f,sqB=0.f;
  const int rowBase = blockIdx.x*256 + wv*64;
  float* h0 = &h0L[wv][0][0];
  float* h1 = &h1L[wv][0][0];

  for(int bt=0; bt<4; ++bt){
    const int rb = rowBase + bt*16;
    h0[(lane&7)*20 + (lane>>3)]     = grouped[(size_t)rb*8 + lane];
    h0[(lane&7)*20 + 8 + (lane>>3)] = grouped[(size_t)(rb+8)*8 + lane];
    __builtin_amdgcn_wave_barrier();
    float a1A[8], a1B[8];
    #pragma unroll
    for(int r=0;r<8;r++){ a1A[r]=bias1a; a1B[r]=bias1b; }
    #pragma unroll
    for(int c=0;c<6;c++){
      float4 lo = *(const float4*)&h0[c*20+r8];
      float4 hi = *(const float4*)&h0[c*20+r8+4];
      fma8(a1A, lo, hi, w1r0[c]);
      fma8(a1B, lo, hi, w1r1[c]);
    }
    #pragma unroll
    for(int r=0;r<8;r++){
      a1A[r]=fmaxf(fmaf(a1A[r],A1a,B1a),0.f);
      a1B[r]=fmaxf(fmaf(a1B[r],A1b,B1b),0.f);
    }
    *(float4*)&h1[c0*20+r8]   = make_float4(a1A[0],a1A[1],a1A[2],a1A[3]);
    *(float4*)&h1[c0*20+r8+4] = make_float4(a1A[4],a1A[5],a1A[6],a1A[7]);
    *(float4*)&h1[c1*20+r8]   = make_float4(a1B[0],a1B[1],a1B[2],a1B[3]);
    *(float4*)&h1[c1*20+r8+4] = make_float4(a1B[4],a1B[5],a1B[6],a1B[7]);
    __builtin_amdgcn_wave_barrier();
    // conv2 with packed FMA accumulators
    v2f a2A[4], a2B[4];
    {
      v2f ba; ba.x=bias2a; ba.y=bias2a;
      v2f bb; bb.x=bias2b; bb.y=bias2b;
      #pragma unroll
      for(int i=0;i<4;i++){ a2A[i]=ba; a2B[i]=bb; }
    }
    #pragma unroll
    for(int c=0;c<64;c++){
      float4 lo = *(const float4*)&h1[c*20+r8];
      float4 hi = *(const float4*)&h1[c*20+r8+4];
      float2 w = ws2[c][li];
      pkfma8(a2A, lo, hi, w.x);
      pkfma8(a2B, lo, hi, w.y);
    }
    #pragma unroll
    for(int i=0;i<4;i++){
      sumA+=a2A[i].x; sqA=fmaf(a2A[i].x,a2A[i].x,sqA);
      sumA+=a2A[i].y; sqA=fmaf(a2A[i].y,a2A[i].y,sqA);
      sumB+=a2B[i].x; sqB=fmaf(a2B[i].x,a2B[i].x,sqB);
      sumB+=a2B[i].y; sqB=fmaf(a2B[i].y,a2B[i].y,sqB);
    }
    if constexpr (STORE){
      #pragma unroll
      for(int r=0;r<8;r++){
        float vA = (r&1) ? a2A[r>>1].y : a2A[r>>1].x;
        float vB = (r&1) ? a2B[r>>1].y : a2B[r>>1].x;
        h2raw[(size_t)(rb + r8 + r)*64 + c0] = vA;
        h2raw[(size_t)(rb + r8 + r)*64 + c1] = vB;
      }
    }
    __builtin_amdgcn_wave_barrier();
  }
  atomicAdd(&sAcc[c0], sumA); atomicAdd(&sAcc[64+c0], sqA);
  atomicAdd(&sAcc[c1], sumB); atomicAdd(&sAcc[64+c1], sqB);
  __syncthreads();
  for(int i=t;i<128;i+=256) atomicAdd(&stats[128+i], sAcc[i]);
}

// ---------------------------------------------------------------------------
// MLP stage 3 SPLIT (R18 structure + packed-FMA conv3): read raw conv2,
// BN2-affine+ReLU, conv3 (w3a regs, w3b via LDS), stats3 + extremes.
// ---------------------------------------------------------------------------
__global__ __launch_bounds__(256) void k_mlp3b(const float* __restrict__ h2raw,
    const float* __restrict__ w3c,const float* __restrict__ b3c,
    const float* __restrict__ g2,const float* __restrict__ bb2,
    const float* __restrict__ g3,
    float* __restrict__ stats,
    float* __restrict__ pre3){
  const int t=threadIdx.x, lane=t&63, wv=t>>6;
  __shared__ float sAcc[256];
  __shared__ __align__(16) float h2L[4][64][20];
  __shared__ float ws3b[64][64];     // [c][lane] = w3[lane+64][c], 16KB
  __shared__ float A2s[64], B2s[64];
  for(int i=t;i<256;i+=256) sAcc[i]=0.f;
  for(int i=t;i<4096;i+=256){
    int c=i>>6, l2=i&63;
    ws3b[c][l2] = w3c[(l2+64)*64 + c];
  }
  if (t<64){
    float mm = stats[128+t]*INV_CNT;
    float vv = stats[192+t]*INV_CNT - mm*mm;
    float aa = g2[t]*rsqrtf(vv+BN_EPS_);
    A2s[t]=aa; B2s[t]=bb2[t]-mm*aa;
  }
  float w3a[64];
  #pragma unroll
  for(int c=0;c<64;c++){ w3a[c]=w3c[lane*64+c]; }
  float bias3a=b3c[lane], bias3b=b3c[lane+64];
  bool mxa=(g3[lane]>=0.f), mxb=(g3[lane+64]>=0.f);
  __syncthreads();
  const int lr = lane>>4;            // 0..3
  const int ch4 = (lane&15)*4;       // 0,4,..,60
  float A2v[4], B2v[4];
  #pragma unroll
  for(int jj=0;jj<4;jj++){ A2v[jj]=A2s[ch4+jj]; B2v[jj]=B2s[ch4+jj]; }

  float sum0=0.f,sq0=0.f,sum1=0.f,sq1=0.f;
  float e0 = mxa? -__builtin_inff(): __builtin_inff();
  float e1 = mxb? -__builtin_inff(): __builtin_inff();
  const int rowBase = blockIdx.x*256 + wv*64;
  float* h2 = &h2L[wv][0][0];

  for(int bt=0; bt<4; ++bt){
    const int rb = rowBase + bt*16;
    // load 16 rows x 64 ch, apply BN2 affine + relu, write LDS [c][20]
    #pragma unroll
    for(int j=0;j<4;j++){
      int rl = j*4 + lr;
      float4 v = *(const float4*)&h2raw[(size_t)(rb+rl)*64 + ch4];
      h2[(ch4+0)*20 + rl] = fmaxf(fmaf(v.x, A2v[0], B2v[0]), 0.f);
      h2[(ch4+1)*20 + rl] = fmaxf(fmaf(v.y, A2v[1], B2v[1]), 0.f);
      h2[(ch4+2)*20 + rl] = fmaxf(fmaf(v.z, A2v[2], B2v[2]), 0.f);
      h2[(ch4+3)*20 + rl] = fmaxf(fmaf(v.w, A2v[3], B2v[3]), 0.f);
    }
    __builtin_amdgcn_wave_barrier();
    // conv3 (full wave, 2ch/lane: ch=lane regs, ch=lane+64 LDS), packed FMA
    #pragma unroll
    for(int s=0;s<2;s++){
      v2f a3a[4], a3b[4];
      {
        v2f ba; ba.x=bias3a; ba.y=bias3a;
        v2f bb; bb.x=bias3b; bb.y=bias3b;
        #pragma unroll
        for(int i=0;i<4;i++){ a3a[i]=ba; a3b[i]=bb; }
      }
      #pragma unroll
      for(int c=0;c<64;c++){
        float4 lo = *(const float4*)&h2[c*20+s*8];
        float4 hi = *(const float4*)&h2[c*20+s*8+4];
        float wb = ws3b[c][lane];
        pkfma8(a3a, lo, hi, w3a[c]);
        pkfma8(a3b, lo, hi, wb);
      }
      #pragma unroll
      for(int r=0;r<8;r++){
        float va = (r&1) ? a3a[r>>1].y : a3a[r>>1].x;
        sum0+=va; sq0=fmaf(va,va,sq0);
        e0 = mxa? fmaxf(e0,va): fminf(e0,va);
        float vb = (r&1) ? a3b[r>>1].y : a3b[r>>1].x;
        sum1+=vb; sq1=fmaf(vb,vb,sq1);
        e1 = mxb? fmaxf(e1,vb): fminf(e1,vb);
      }
    }
    if (bt&1){
      int gg = (rowBase>>5) + (bt>>1);
      pre3[(size_t)gg*128 + lane]      = e0;
      pre3[(size_t)gg*128 + 64 + lane] = e1;
      e0 = mxa? -__builtin_inff(): __builtin_inff();
      e1 = mxb? -__builtin_inff(): __builtin_inff();
    }
    __builtin_amdgcn_wave_barrier();
  }
  atomicAdd(&sAcc[lane],      sum0);
  atomicAdd(&sAcc[64+lane],   sum1);
  atomicAdd(&sAcc[128+lane],  sq0);
  atomicAdd(&sAcc[192+lane],  sq1);
  __syncthreads();
  for(int i=t;i<128;i+=256) atomicAdd(&stats[256+i], sAcc[i]);
  for(int i=t;i<128;i+=256) atomicAdd(&stats[384+i], sAcc[128+i]);
}

// ---------------------------------------------------------------------------
// MLP stage 3 MONOLITHIC (fallback when ws too small) — unchanged
// ---------------------------------------------------------------------------
__global__ __launch_bounds__(256) void k_mlp3(const float* __restrict__ grouped,
    const float* __restrict__ w1c,const float* __restrict__ b1c,
    const float* __restrict__ w2c,const float* __restrict__ b2c,
    const float* __restrict__ w3c,const float* __restrict__ b3c,
    const float* __restrict__ g1,const float* __restrict__ bb1,
    const float* __restrict__ g2,const float* __restrict__ bb2,
    const float* __restrict__ g3,
    float* __restrict__ stats,
    float* __restrict__ pre3){
  const int t=threadIdx.x, lane=t&63, wv=t>>6;
  const int h=lane>>5, li=lane&31, c0=li, c1=li+32, r8=h*8;
  __shared__ float sAcc[256];
  __shared__ __align__(16) float h0L[4][8][20];
  __shared__ __align__(16) float h1L[4][64][20];
  __shared__ __align__(16) float h2L[4][64][20];
  __shared__ __align__(8)  float2 ws2[64][32];
  for(int i=t;i<256;i+=256) sAcc[i]=0.f;
  for(int i=t;i<2048;i+=256){
    int c=i>>5, l2=i&31;
    ws2[c][l2] = make_float2(w2c[l2*64+c], w2c[(l2+32)*64+c]);
  }

  float w1r0[6], w1r1[6];
  #pragma unroll
  for(int c=0;c<6;c++){ w1r0[c]=w1c[c0*6+c]; w1r1[c]=w1c[c1*6+c]; }
  float bias1a=b1c[c0], bias1b=b1c[c1];
  float mm, vv;
  mm = stats[c0]*INV_CNT;  vv = stats[64+c0]*INV_CNT - mm*mm;
  float A1a = g1[c0]*rsqrtf(vv+BN_EPS_); float B1a = bb1[c0]-mm*A1a;
  mm = stats[c1]*INV_CNT;  vv = stats[64+c1]*INV_CNT - mm*mm;
  float A1b = g1[c1]*rsqrtf(vv+BN_EPS_); float B1b = bb1[c1]-mm*A1b;
  float bias2a=b2c[c0], bias2b=b2c[c1];
  mm = stats[128+c0]*INV_CNT; vv = stats[192+c0]*INV_CNT - mm*mm;
  float A2a = g2[c0]*rsqrtf(vv+BN_EPS_); float B2a = bb2[c0]-mm*A2a;
  mm = stats[128+c1]*INV_CNT; vv = stats[192+c1]*INV_CNT - mm*mm;
  float A2b = g2[c1]*rsqrtf(vv+BN_EPS_); float B2b = bb2[c1]-mm*A2b;
  float w3a[64], w3b[64];
  #pragma unroll
  for(int c=0;c<64;c++){ w3a[c]=w3c[lane*64+c]; w3b[c]=w3c[(lane+64)*64+c]; }
  float bias3a=b3c[lane], bias3b=b3c[lane+64];
  bool mxa=(g3[lane]>=0.f), mxb=(g3[lane+64]>=0.f);
  __syncthreads();

  float sum0=0.f,sq0=0.f,sum1=0.f,sq1=0.f;
  float e0 = mxa? -__builtin_inff(): __builtin_inff();
  float e1 = mxb? -__builtin_inff(): __builtin_inff();
  const int rowBase = blockIdx.x*256 + wv*64;
  float* h0 = &h0L[wv][0][0];
  float* h1 = &h1L[wv][0][0];
  float* h2 = &h2L[wv][0][0];

  for(int bt=0; bt<4; ++bt){
    const int rb = rowBase + bt*16;
    h0[(lane&7)*20 + (lane>>3)]     = grouped[(size_t)rb*8 + lane];
    h0[(lane&7)*20 + 8 + (lane>>3)] = grouped[(size_t)(rb+8)*8 + lane];
    __builtin_amdgcn_wave_barrier();
    float a1A[8], a1B[8];
    #pragma unroll
    for(int r=0;r<8;r++){ a1A[r]=bias1a; a1B[r]=bias1b; }
    #pragma unroll
    for(int c=0;c<6;c++){
      float4 lo = *(const float4*)&h0[c*20+r8];
      float4 hi = *(const float4*)&h0[c*20+r8+4];
      fma8(a1A, lo, hi, w1r0[c]);
      fma8(a1B, lo, hi, w1r1[c]);
    }
    #pragma unroll
    for(int r=0;r<8;r++){
      a1A[r]=fmaxf(fmaf(a1A[r],A1a,B1a),0.f);
      a1B[r]=fmaxf(fmaf(a1B[r],A1b,B1b),0.f);
    }
    *(float4*)&h1[c0*20+r8]   = make_float4(a1A[0],a1A[1],a1A[2],a1A[3]);
    *(float4*)&h1[c0*20+r8+4] = make_float4(a1A[4],a1A[5],a1A[6],a1A[7]);
    *(float4*)&h1[c1*20+r8]   = make_float4(a1B[0],a1B[1],a1B[2],a1B[3]);
    *(float4*)&h1[c1*20+r8+4] = make_float4(a1B[4],a1B[5],a1B[6],a1B[7]);
    __builtin_amdgcn_wave_barrier();
    float a2A[8], a2B[8];
    #pragma unroll
    for(int r=0;r<8;r++){ a2A[r]=bias2a; a2B[r]=bias2b; }
    #pragma unroll
    for(int c=0;c<64;c++){
      float4 lo = *(const float4*)&h1[c*20+r8];
      float4 hi = *(const float4*)&h1[c*20+r8+4];
      float2 w = ws2[c][li];
      fma8(a2A, lo, hi, w.x);
      fma8(a2B, lo, hi, w.y);
    }
    #pragma unroll
    for(int r=0;r<8;r++){
      a2A[r]=fmaxf(fmaf(a2A[r],A2a,B2a),0.f);
      a2B[r]=fmaxf(fmaf(a2B[r],A2b,B2b),0.f);
    }
    *(float4*)&h2[c0*20+r8]   = make_float4(a2A[0],a2A[1],a2A[2],a2A[3]);
    *(float4*)&h2[c0*20+r8+4] = make_float4(a2A[4],a2A[5],a2A[6],a2A[7]);
    *(float4*)&h2[c1*20+r8]   = make_float4(a2B[0],a2B[1],a2B[2],a2B[3]);
    *(float4*)&h2[c1*20+r8+4] = make_float4(a2B[4],a2B[5],a2B[6],a2B[7]);
    __builtin_amdgcn_wave_barrier();
    #pragma unroll
    for(int s=0;s<2;s++){
      float a3a[8], a3b[8];
      #pragma unroll
      for(int r=0;r<8;r++){ a3a[r]=bias3a; a3b[r]=bias3b; }
      #pragma unroll
      for(int c=0;c<64;c++){
        float4 lo = *(const float4*)&h2[c*20+s*8];
        float4 hi = *(const float4*)&h2[c*20+s*8+4];
        fma8(a3a, lo, hi, w3a[c]);
        fma8(a3b, lo, hi, w3b[c]);
      }
      #pragma unroll
      for(int r=0;r<8;r++){
        float va=a3a[r]; sum0+=va; sq0=fmaf(va,va,sq0);
        e0 = mxa? fmaxf(e0,va): fminf(e0,va);
        float vb=a3b[r]; sum1+=vb; sq1=fmaf(vb,vb,sq1);
        e1 = mxb? fmaxf(e1,vb): fminf(e1,vb);
      }
    }
    if (bt&1){
      int gg = (rowBase>>5) + (bt>>1);
      pre3[(size_t)gg*128 + lane]      = e0;
      pre3[(size_t)gg*128 + 64 + lane] = e1;
      e0 = mxa? -__builtin_inff(): __builtin_inff();
      e1 = mxb? -__builtin_inff(): __builtin_inff();
    }
    __builtin_amdgcn_wave_barrier();
  }
  atomicAdd(&sAcc[lane],      sum0);
  atomicAdd(&sAcc[64+lane],   sum1);
  atomicAdd(&sAcc[128+lane],  sq0);
  atomicAdd(&sAcc[192+lane],  sq1);
  __syncthreads();
  for(int i=t;i<128;i+=256) atomicAdd(&stats[256+i], sAcc[i]);
  for(int i=t;i<128;i+=256) atomicAdd(&stats[384+i], sAcc[128+i]);
}

// ---------------------------------------------------------------------------
// Final: BN3 affine + relu on per-group extremes, transpose to [B,128,S]
// ---------------------------------------------------------------------------
__global__ __launch_bounds__(256) void k_final(const float* __restrict__ pre3,
                                               const float* __restrict__ stats,
                                               const float* __restrict__ g3,
                                               const float* __restrict__ bb3,
                                               float* __restrict__ outNP){
  __shared__ float A3[128], B3[128];
  __shared__ float til[128][65];
  const int t=threadIdx.x;
  if (t<128){
    float mm = stats[256+t]*INV_CNT;
    float vv = stats[384+t]*INV_CNT - mm*mm;
    float aa = g3[t]*rsqrtf(vv+BN_EPS_);
    A3[t]=aa; B3[t]=bb3[t]-mm*aa;
  }
  const int b = blockIdx.x>>4, s0=(blockIdx.x&15)*64;
  #pragma unroll
  for(int i=0;i<32;i++){
    int lin=i*256+t; int sl=lin>>7, o=lin&127;
    til[o][sl]=pre3[((size_t)b*NS + s0 + sl)*128 + o];
  }
  __syncthreads();
  #pragma unroll
  for(int i=0;i<32;i++){
    int lin=i*256+t; int o=lin>>6, sl=lin&63;
    outNP[(size_t)b*128*NS + (size_t)o*NS + s0 + sl] =
        fmaxf(fmaf(til[o][sl],A3[o],B3[o]),0.f);
  }
}

extern "C" void kernel_launch(void* const* d_in, const int* in_sizes, int n_in,
                              void* d_out, int out_size, void* d_ws, size_t ws_size,
                              hipStream_t stream){
  const float* xyz=(const float*)d_in[0];
  const float* pts=(const float*)d_in[1];
  const float* w1 =(const float*)d_in[2];
  const float* b1 =(const float*)d_in[3];
  const float* g1 =(const float*)d_in[4];
  const float* bb1=(const float*)d_in[5];
  const float* w2 =(const float*)d_in[6];
  const float* b2 =(const float*)d_in[7];
  const float* g2 =(const float*)d_in[8];
  const float* bb2=(const float*)d_in[9];
  const float* w3 =(const float*)d_in[10];
  const float* b3 =(const float*)d_in[11];
  const float* g3 =(const float*)d_in[12];
  const float* bb3=(const float*)d_in[13];
  float* out=(float*)d_out;
  float* outNewXyz=out;
  float* outNP=out + (size_t)NB*3*NS;

  char* ws=(char*)d_ws;
  const size_t BASE = 4096 + 65536 + 262144 + 16777216 + 2097152; // ~19.2MB
  float* stats  =(float*)ws;                                   // 512 floats
  int*   fpsIdx =(int*)  (ws + 4096);                          // 16K ints
  float* norms  =(float*)(ws + 4096 + 65536);                  // 64K floats
  float* grouped=(float*)(ws + 4096 + 65536 + 262144);         // 4M floats
  float* pre3   =(float*)(ws + 4096 + 65536 + 262144 + 16777216); // 2M floats
  float* h2raw  =(float*)(ws + BASE);                          // 33.5M floats (134MB)
  const bool split = ws_size >= BASE + 134217728ull;

  k_fps  <<<dim3(NB),       dim3(256),  0, stream>>>(xyz, fpsIdx, norms, outNewXyz, stats);
  k_group<<<dim3(NB*NS/4),  dim3(256),  0, stream>>>(xyz, pts, norms, fpsIdx, grouped);
  k_mlp1 <<<dim3(2048), dim3(256), 0, stream>>>(grouped, w1,b1, stats);
  if (split){
    k_mlp2<1><<<dim3(2048), dim3(256), 0, stream>>>(grouped, w1,b1,w2,b2, g1,bb1, stats, h2raw);
    k_mlp3b  <<<dim3(2048), dim3(256), 0, stream>>>(h2raw, w3,b3, g2,bb2, g3, stats, pre3);
  } else {
    k_mlp2<0><<<dim3(2048), dim3(256), 0, stream>>>(grouped, w1,b1,w2,b2, g1,bb1, stats, h2raw);
    k_mlp3   <<<dim3(2048), dim3(256), 0, stream>>>(grouped, w1,b1,w2,b2,w3,b3, g1,bb1,g2,bb2,g3, stats, pre3);
  }
  k_final<<<dim3(256),  dim3(256), 0, stream>>>(pre3, stats, g3, bb3, outNP);
}

// Round 20
// 979.834 us; speedup vs baseline: 1.1497x; 1.1497x over previous
//
#include <hip/hip_runtime.h>
#include <stdint.h>

// Problem constants
#define NB 16
#define NN 4096
#define NS 1024
#define NK 32
#define INV_CNT (1.0f/524288.0f)   // 1/(B*S*K)
#define BN_EPS_ 1e-5f

// exact-rounding helpers (block FMA contraction to match numpy elementwise semantics)
__device__ __forceinline__ float frn_mul(float a,float b){ return __fmul_rn(a,b); }
__device__ __forceinline__ float frn_add(float a,float b){ return __fadd_rn(a,b); }
__device__ __forceinline__ float frn_sub(float a,float b){ return __fsub_rn(a,b); }

__device__ __forceinline__ unsigned long long ullmax_(unsigned long long a, unsigned long long b){ return a>b?a:b; }

typedef float v2f __attribute__((ext_vector_type(2)));

// u64 DPP shift/bcast: both halves use same ctrl => coherent source lane.
template<int CTRL>
__device__ __forceinline__ unsigned long long dpp_max_u64(unsigned long long v){
  int lo = __builtin_amdgcn_update_dpp((int)(unsigned)v, (int)(unsigned)v, CTRL, 0xf, 0xf, false);
  int hi = __builtin_amdgcn_update_dpp((int)(unsigned)(v>>32), (int)(unsigned)(v>>32), CTRL, 0xf, 0xf, false);
  unsigned long long o = (((unsigned long long)(unsigned)hi)<<32) | (unsigned long long)(unsigned)lo;
  return (o>v)?o:v;
}

// ---------------------------------------------------------------------------
// FPS v7 (settled floor ~620-630us). Block 0 also zeroes stats[].
// Journal: pk-f32 scan (v7) kept — it computes natively into v2f so pk ops
// are free. R19 lesson: pk only pays when data is PRODUCED packed; repacking
// float4->v2f costs movs (conv pk experiment regressed 980->1127, reverted).
// ---------------------------------------------------------------------------
__global__ __launch_bounds__(256) void k_fps(const float* __restrict__ xyz,
                                             int* __restrict__ fpsIdx,
                                             float* __restrict__ norms,
                                             float* __restrict__ outNewXyz,
                                             float* __restrict__ stats){
  const int b = blockIdx.x;
  const float* bxp = xyz + (size_t)b*3*NN;
  const int t = threadIdx.x, lane = t&63, wv = t>>6;
  if (b==0){ stats[t]=0.f; stats[256+t]=0.f; }
  __shared__ __align__(16) float4 sxyz[NN];           // 64 KB
  __shared__ __align__(32) unsigned long long red[2][4];
  v2f px2[8], py2[8], pz2[8], dd2[8];
  #pragma unroll
  for(int j=0;j<8;j++){
    #pragma unroll
    for(int k=0;k<2;k++){
      int n = t + (2*j+k)*256;
      float x=bxp[n], y=bxp[NN+n], z=bxp[2*NN+n];
      if(k==0){ px2[j].x=x; py2[j].x=y; pz2[j].x=z; }
      else    { px2[j].y=x; py2[j].y=y; pz2[j].y=z; }
      float nr = frn_add(frn_add(frn_mul(x,x),frn_mul(y,y)),frn_mul(z,z));
      norms[(size_t)b*NN+n]=nr;
      sxyz[n] = make_float4(x,y,z,0.f);
    }
    dd2[j].x=1e10f; dd2[j].y=1e10f;
  }
  const int rnb = NN-1-t;
  __syncthreads();
  int cur = 0;
  for(int it=0; it<NS; ++it){
    float4 c = sxyz[cur];                              // broadcast LDS read
    if (t==0){
      fpsIdx[b*NS+it]=cur;
      outNewXyz[(size_t)b*3*NS + it]        = c.x;
      outNewXyz[(size_t)b*3*NS + NS + it]   = c.y;
      outNewXyz[(size_t)b*3*NS + 2*NS + it] = c.z;
    }
    float bestv = -1.0f; int bestr = 0;
    {
      #pragma clang fp contract(off)
      v2f cx2; cx2.x=c.x; cx2.y=c.x;
      v2f cy2; cy2.x=c.y; cy2.y=c.y;
      v2f cz2; cz2.x=c.z; cz2.y=c.z;
      #pragma unroll
      for(int j=0;j<8;j++){
        v2f dx = px2[j] - cx2;
        v2f dy = py2[j] - cy2;
        v2f dz = pz2[j] - cz2;
        v2f d  = ((dx*dx) + (dy*dy)) + (dz*dz);   // pk_mul/pk_add, RN, no FMA
        float nd0 = fminf(dd2[j].x, d.x);
        dd2[j].x = nd0;
        bool g0 = nd0 > bestv;    // ascending i + strict > => smallest n on tie
        bestv = g0?nd0:bestv; bestr = g0?(rnb-((2*j)<<8)):bestr;
        float nd1 = fminf(dd2[j].y, d.y);
        dd2[j].y = nd1;
        bool g1 = nd1 > bestv;
        bestv = g1?nd1:bestv; bestr = g1?(rnb-((2*j+1)<<8)):bestr;
      }
    }
    unsigned long long best = (((unsigned long long)__float_as_uint(bestv))<<32)
                            | (unsigned long long)(unsigned)bestr;
    best = dpp_max_u64<0x111>(best);
    best = dpp_max_u64<0x112>(best);
    best = dpp_max_u64<0x114>(best);
    best = dpp_max_u64<0x118>(best);
    best = dpp_max_u64<0x142>(best);
    best = dpp_max_u64<0x143>(best);
    if (lane==63) red[it&1][wv]=best;
    __syncthreads();
    unsigned long long v = ullmax_(ullmax_(red[it&1][0], red[it&1][1]),
                                   ullmax_(red[it&1][2], red[it&1][3]));
    cur = NN-1-(int)(unsigned)(v & 0xffffffffull);
    cur = __builtin_amdgcn_readfirstlane(cur);
  }
}

// ---------------------------------------------------------------------------
// Ball query + grouping (unchanged)
// ---------------------------------------------------------------------------
__global__ __launch_bounds__(256) void k_group(const float* __restrict__ xyz,
                                               const float* __restrict__ pts,
                                               const float* __restrict__ norms,
                                               const int* __restrict__ fpsIdx,
                                               float* __restrict__ grouped){
  const int t=threadIdx.x, lane=t&63, wv=t>>6;
  const int g = blockIdx.x*4 + wv;            // 0..16383
  const int b = g>>10, s = g&1023;
  const float* bx = xyz + (size_t)b*3*NN;
  const float* bp = pts + (size_t)b*3*NN;
  int ci = __builtin_amdgcn_readfirstlane(fpsIdx[b*NS+s]);
  float cx=bx[ci], cy=bx[NN+ci], cz=bx[2*NN+ci];
  float cn2 = norms[(size_t)b*NN+ci];
  __shared__ __align__(16) float stage[4][NK][8];
  int cnt=0;
  for(int ch=0; ch<NN/64; ++ch){
    if (cnt>=NK) break;
    int n = ch*64 + lane;
    float x=bx[n], y=bx[NN+n], z=bx[2*NN+n];
    float pn2 = norms[(size_t)b*NN+n];
    float dot = frn_add(frn_add(frn_mul(cx,x),frn_mul(cy,y)),frn_mul(cz,z));
    float sqr = frn_sub(frn_add(cn2,pn2), frn_mul(2.0f,dot));
    bool ok = !(sqr > 0.04f);                 // in-ball iff sqr <= R^2
    unsigned long long m = __ballot(ok);
    int pos = cnt + __popcll(m & ((1ull<<lane)-1ull));
    if (ok && pos<NK){
      float q0=bp[n], q1=bp[NN+n], q2=bp[2*NN+n];
      float* r = &stage[wv][pos][0];
      r[0]=frn_sub(x,cx); r[1]=frn_sub(y,cy); r[2]=frn_sub(z,cz);
      r[3]=q0; r[4]=q1; r[5]=q2; r[6]=0.f; r[7]=0.f;
    }
    cnt += __popcll(m);
  }
  __syncthreads();
  int c2 = cnt<NK?cnt:NK;
  if (lane>=c2 && lane<NK){
    #pragma unroll
    for(int j=0;j<8;j++) stage[wv][lane][j]=stage[wv][0][j];
  }
  __syncthreads();
  float4* dst = (float4*)(grouped + (size_t)g*NK*8);
  dst[lane] = ((const float4*)&stage[wv][0][0])[lane];
}

__device__ __forceinline__ void fma8(float* av, float4 lo, float4 hi, float w){
  av[0]=fmaf(lo.x,w,av[0]); av[1]=fmaf(lo.y,w,av[1]);
  av[2]=fmaf(lo.z,w,av[2]); av[3]=fmaf(lo.w,w,av[3]);
  av[4]=fmaf(hi.x,w,av[4]); av[5]=fmaf(hi.y,w,av[5]);
  av[6]=fmaf(hi.z,w,av[6]); av[7]=fmaf(hi.w,w,av[7]);
}

// ---------------------------------------------------------------------------
// MLP stage 1: conv1 -> stats[0..64)=sum, [64..128)=sq. (unchanged)
// ---------------------------------------------------------------------------
__global__ __launch_bounds__(256) void k_mlp1(const float* __restrict__ grouped,
    const float* __restrict__ w1c, const float* __restrict__ b1c,
    float* __restrict__ stats){
  const int t=threadIdx.x, lane=t&63, wv=t>>6;
  __shared__ float sAcc[128];
  __shared__ __align__(16) float h0L[4][8][12];
  for(int i=t;i<128;i+=256) sAcc[i]=0.f;
  float w1r[6];
  #pragma unroll
  for(int c=0;c<6;c++) w1r[c]=w1c[lane*6+c];
  float bias1=b1c[lane];
  __syncthreads();
  float sum0=0.f, sq0=0.f;
  const int rowBase = blockIdx.x*256 + wv*64;
  float* h0 = &h0L[wv][0][0];
  for(int bt=0; bt<8; ++bt){
    const int rb = rowBase + bt*8;
    h0[(lane&7)*12 + (lane>>3)] = grouped[(size_t)rb*8 + lane];
    __builtin_amdgcn_wave_barrier();
    float a1[8];
    #pragma unroll
    for(int r=0;r<8;r++) a1[r]=bias1;
    #pragma unroll
    for(int c=0;c<6;c++){
      float4 lo = *(const float4*)&h0[c*12+0];
      float4 hi = *(const float4*)&h0[c*12+4];
      fma8(a1, lo, hi, w1r[c]);
    }
    #pragma unroll
    for(int r=0;r<8;r++){ sum0+=a1[r]; sq0=fmaf(a1[r],a1[r],sq0); }
    __builtin_amdgcn_wave_barrier();
  }
  atomicAdd(&sAcc[lane], sum0); atomicAdd(&sAcc[64+lane], sq0);
  __syncthreads();
  for(int i=t;i<128;i+=256) atomicAdd(&stats[i], sAcc[i]);
}

// ---------------------------------------------------------------------------
// MLP stage 2: conv1,bn1,relu,conv2 -> stats[128..192)=sum,[192..256)=sq.
// STORE=1 additionally writes raw conv2 output to h2raw[row][64].
// (R18-exact: fma8 scalar FMA chains — pk repack experiment reverted.)
// ---------------------------------------------------------------------------
template<int STORE>
__global__ __launch_bounds__(256) void k_mlp2(const float* __restrict__ grouped,
    const float* __restrict__ w1c,const float* __restrict__ b1c,
    const float* __restrict__ w2c,const float* __restrict__ b2c,
    const float* __restrict__ g1,const float* __restrict__ bb1,
    float* __restrict__ stats,
    float* __restrict__ h2raw){
  const int t=threadIdx.x, lane=t&63, wv=t>>6;
  const int h=lane>>5, li=lane&31, c0=li, c1=li+32, r8=h*8;
  __shared__ float sAcc[128];
  __shared__ __align__(16) float h0L[4][8][20];
  __shared__ __align__(16) float h1L[4][64][20];
  __shared__ __align__(8)  float2 ws2[64][32];   // [in c][li] = {w2[li][c], w2[li+32][c]}
  for(int i=t;i<128;i+=256) sAcc[i]=0.f;
  for(int i=t;i<2048;i+=256){
    int c=i>>5, l2=i&31;
    ws2[c][l2] = make_float2(w2c[l2*64+c], w2c[(l2+32)*64+c]);
  }

  float w1r0[6], w1r1[6];
  #pragma unroll
  for(int c=0;c<6;c++){ w1r0[c]=w1c[c0*6+c]; w1r1[c]=w1c[c1*6+c]; }
  float bias1a=b1c[c0], bias1b=b1c[c1];
  float mmA = stats[c0]*INV_CNT;
  float vvA = stats[64+c0]*INV_CNT - mmA*mmA;
  float A1a = g1[c0]*rsqrtf(vvA+BN_EPS_);
  float B1a = bb1[c0]-mmA*A1a;
  float mmB = stats[c1]*INV_CNT;
  float vvB = stats[64+c1]*INV_CNT - mmB*mmB;
  float A1b = g1[c1]*rsqrtf(vvB+BN_EPS_);
  float B1b = bb1[c1]-mmB*A1b;
  float bias2a=b2c[c0], bias2b=b2c[c1];
  __syncthreads();

  float sumA=0.f,sqA=0.f,sumB=0.f,sqB=0.f;
  const int rowBase = blockIdx.x*256 + wv*64;
  float* h0 = &h0L[wv][0][0];
  float* h1 = &h1L[wv][0][0];

  for(int bt=0; bt<4; ++bt){
    const int rb = rowBase + bt*16;
    h0[(lane&7)*20 + (lane>>3)]     = grouped[(size_t)rb*8 + lane];
    h0[(lane&7)*20 + 8 + (lane>>3)] = grouped[(size_t)(rb+8)*8 + lane];
    __builtin_amdgcn_wave_barrier();
    float a1A[8], a1B[8];
    #pragma unroll
    for(int r=0;r<8;r++){ a1A[r]=bias1a; a1B[r]=bias1b; }
    #pragma unroll
    for(int c=0;c<6;c++){
      float4 lo = *(const float4*)&h0[c*20+r8];
      float4 hi = *(const float4*)&h0[c*20+r8+4];
      fma8(a1A, lo, hi, w1r0[c]);
      fma8(a1B, lo, hi, w1r1[c]);
    }
    #pragma unroll
    for(int r=0;r<8;r++){
      a1A[r]=fmaxf(fmaf(a1A[r],A1a,B1a),0.f);
      a1B[r]=fmaxf(fmaf(a1B[r],A1b,B1b),0.f);
    }
    *(float4*)&h1[c0*20+r8]   = make_float4(a1A[0],a1A[1],a1A[2],a1A[3]);
    *(float4*)&h1[c0*20+r8+4] = make_float4(a1A[4],a1A[5],a1A[6],a1A[7]);
    *(float4*)&h1[c1*20+r8]   = make_float4(a1B[0],a1B[1],a1B[2],a1B[3]);
    *(float4*)&h1[c1*20+r8+4] = make_float4(a1B[4],a1B[5],a1B[6],a1B[7]);
    __builtin_amdgcn_wave_barrier();
    float a2A[8], a2B[8];
    #pragma unroll
    for(int r=0;r<8;r++){ a2A[r]=bias2a; a2B[r]=bias2b; }
    #pragma unroll
    for(int c=0;c<64;c++){
      float4 lo = *(const float4*)&h1[c*20+r8];
      float4 hi = *(const float4*)&h1[c*20+r8+4];
      float2 w = ws2[c][li];
      fma8(a2A, lo, hi, w.x);
      fma8(a2B, lo, hi, w.y);
    }
    #pragma unroll
    for(int r=0;r<8;r++){
      sumA+=a2A[r]; sqA=fmaf(a2A[r],a2A[r],sqA);
      sumB+=a2B[r]; sqB=fmaf(a2B[r],a2B[r],sqB);
    }
    if constexpr (STORE){
      #pragma unroll
      for(int r=0;r<8;r++){
        h2raw[(size_t)(rb + r8 + r)*64 + c0] = a2A[r];
        h2raw[(size_t)(rb + r8 + r)*64 + c1] = a2B[r];
      }
    }
    __builtin_amdgcn_wave_barrier();
  }
  atomicAdd(&sAcc[c0], sumA); atomicAdd(&sAcc[64+c0], sqA);
  atomicAdd(&sAcc[c1], sumB); atomicAdd(&sAcc[64+c1], sqB);
  __syncthreads();
  for(int i=t;i<128;i+=256) atomicAdd(&stats[128+i], sAcc[i]);
}

// ---------------------------------------------------------------------------
// MLP stage 3 SPLIT (R18-exact): read raw conv2 (h2raw), BN2-affine+ReLU,
// conv3 (w3a regs, w3b via LDS ws3b), stats3 + extremes.
// ---------------------------------------------------------------------------
__global__ __launch_bounds__(256) void k_mlp3b(const float* __restrict__ h2raw,
    const float* __restrict__ w3c,const float* __restrict__ b3c,
    const float* __restrict__ g2,const float* __restrict__ bb2,
    const float* __restrict__ g3,
    float* __restrict__ stats,
    float* __restrict__ pre3){
  const int t=threadIdx.x, lane=t&63, wv=t>>6;
  __shared__ float sAcc[256];
  __shared__ __align__(16) float h2L[4][64][20];
  __shared__ float ws3b[64][64];     // [c][lane] = w3[lane+64][c], 16KB
  __shared__ float A2s[64], B2s[64];
  for(int i=t;i<256;i+=256) sAcc[i]=0.f;
  for(int i=t;i<4096;i+=256){
    int c=i>>6, l2=i&63;
    ws3b[c][l2] = w3c[(l2+64)*64 + c];
  }
  if (t<64){
    float mm = stats[128+t]*INV_CNT;
    float vv = stats[192+t]*INV_CNT - mm*mm;
    float aa = g2[t]*rsqrtf(vv+BN_EPS_);
    A2s[t]=aa; B2s[t]=bb2[t]-mm*aa;
  }
  float w3a[64];
  #pragma unroll
  for(int c=0;c<64;c++){ w3a[c]=w3c[lane*64+c]; }
  float bias3a=b3c[lane], bias3b=b3c[lane+64];
  bool mxa=(g3[lane]>=0.f), mxb=(g3[lane+64]>=0.f);
  __syncthreads();
  const int lr = lane>>4;            // 0..3
  const int ch4 = (lane&15)*4;       // 0,4,..,60
  float A2v[4], B2v[4];
  #pragma unroll
  for(int jj=0;jj<4;jj++){ A2v[jj]=A2s[ch4+jj]; B2v[jj]=B2s[ch4+jj]; }

  float sum0=0.f,sq0=0.f,sum1=0.f,sq1=0.f;
  float e0 = mxa? -__builtin_inff(): __builtin_inff();
  float e1 = mxb? -__builtin_inff(): __builtin_inff();
  const int rowBase = blockIdx.x*256 + wv*64;
  float* h2 = &h2L[wv][0][0];

  for(int bt=0; bt<4; ++bt){
    const int rb = rowBase + bt*16;
    // load 16 rows x 64 ch, apply BN2 affine + relu, write LDS [c][20]
    #pragma unroll
    for(int j=0;j<4;j++){
      int rl = j*4 + lr;
      float4 v = *(const float4*)&h2raw[(size_t)(rb+rl)*64 + ch4];
      h2[(ch4+0)*20 + rl] = fmaxf(fmaf(v.x, A2v[0], B2v[0]), 0.f);
      h2[(ch4+1)*20 + rl] = fmaxf(fmaf(v.y, A2v[1], B2v[1]), 0.f);
      h2[(ch4+2)*20 + rl] = fmaxf(fmaf(v.z, A2v[2], B2v[2]), 0.f);
      h2[(ch4+3)*20 + rl] = fmaxf(fmaf(v.w, A2v[3], B2v[3]), 0.f);
    }
    __builtin_amdgcn_wave_barrier();
    // conv3 (full wave, 2ch/lane: ch=lane from regs, ch=lane+64 from LDS)
    #pragma unroll
    for(int s=0;s<2;s++){
      float a3a[8], a3b[8];
      #pragma unroll
      for(int r=0;r<8;r++){ a3a[r]=bias3a; a3b[r]=bias3b; }
      #pragma unroll
      for(int c=0;c<64;c++){
        float4 lo = *(const float4*)&h2[c*20+s*8];
        float4 hi = *(const float4*)&h2[c*20+s*8+4];
        float wb = ws3b[c][lane];
        fma8(a3a, lo, hi, w3a[c]);
        fma8(a3b, lo, hi, wb);
      }
      #pragma unroll
      for(int r=0;r<8;r++){
        float va=a3a[r]; sum0+=va; sq0=fmaf(va,va,sq0);
        e0 = mxa? fmaxf(e0,va): fminf(e0,va);
        float vb=a3b[r]; sum1+=vb; sq1=fmaf(vb,vb,sq1);
        e1 = mxb? fmaxf(e1,vb): fminf(e1,vb);
      }
    }
    if (bt&1){
      int gg = (rowBase>>5) + (bt>>1);
      pre3[(size_t)gg*128 + lane]      = e0;
      pre3[(size_t)gg*128 + 64 + lane] = e1;
      e0 = mxa? -__builtin_inff(): __builtin_inff();
      e1 = mxb? -__builtin_inff(): __builtin_inff();
    }
    __builtin_amdgcn_wave_barrier();
  }
  atomicAdd(&sAcc[lane],      sum0);
  atomicAdd(&sAcc[64+lane],   sum1);
  atomicAdd(&sAcc[128+lane],  sq0);
  atomicAdd(&sAcc[192+lane],  sq1);
  __syncthreads();
  for(int i=t;i<128;i+=256) atomicAdd(&stats[256+i], sAcc[i]);
  for(int i=t;i<128;i+=256) atomicAdd(&stats[384+i], sAcc[128+i]);
}

// ---------------------------------------------------------------------------
// MLP stage 3 MONOLITHIC (fallback when ws too small) — unchanged
// ---------------------------------------------------------------------------
__global__ __launch_bounds__(256) void k_mlp3(const float* __restrict__ grouped,
    const float* __restrict__ w1c,const float* __restrict__ b1c,
    const float* __restrict__ w2c,const float* __restrict__ b2c,
    const float* __restrict__ w3c,const float* __restrict__ b3c,
    const float* __restrict__ g1,const float* __restrict__ bb1,
    const float* __restrict__ g2,const float* __restrict__ bb2,
    const float* __restrict__ g3,
    float* __restrict__ stats,
    float* __restrict__ pre3){
  const int t=threadIdx.x, lane=t&63, wv=t>>6;
  const int h=lane>>5, li=lane&31, c0=li, c1=li+32, r8=h*8;
  __shared__ float sAcc[256];
  __shared__ __align__(16) float h0L[4][8][20];
  __shared__ __align__(16) float h1L[4][64][20];
  __shared__ __align__(16) float h2L[4][64][20];
  __shared__ __align__(8)  float2 ws2[64][32];
  for(int i=t;i<256;i+=256) sAcc[i]=0.f;
  for(int i=t;i<2048;i+=256){
    int c=i>>5, l2=i&31;
    ws2[c][l2] = make_float2(w2c[l2*64+c], w2c[(l2+32)*64+c]);
  }

  float w1r0[6], w1r1[6];
  #pragma unroll
  for(int c=0;c<6;c++){ w1r0[c]=w1c[c0*6+c]; w1r1[c]=w1c[c1*6+c]; }
  float bias1a=b1c[c0], bias1b=b1c[c1];
  float mm, vv;
  mm = stats[c0]*INV_CNT;  vv = stats[64+c0]*INV_CNT - mm*mm;
  float A1a = g1[c0]*rsqrtf(vv+BN_EPS_); float B1a = bb1[c0]-mm*A1a;
  mm = stats[c1]*INV_CNT;  vv = stats[64+c1]*INV_CNT - mm*mm;
  float A1b = g1[c1]*rsqrtf(vv+BN_EPS_); float B1b = bb1[c1]-mm*A1b;
  float bias2a=b2c[c0], bias2b=b2c[c1];
  mm = stats[128+c0]*INV_CNT; vv = stats[192+c0]*INV_CNT - mm*mm;
  float A2a = g2[c0]*rsqrtf(vv+BN_EPS_); float B2a = bb2[c0]-mm*A2a;
  mm = stats[128+c1]*INV_CNT; vv = stats[192+c1]*INV_CNT - mm*mm;
  float A2b = g2[c1]*rsqrtf(vv+BN_EPS_); float B2b = bb2[c1]-mm*A2b;
  float w3a[64], w3b[64];
  #pragma unroll
  for(int c=0;c<64;c++){ w3a[c]=w3c[lane*64+c]; w3b[c]=w3c[(lane+64)*64+c]; }
  float bias3a=b3c[lane], bias3b=b3c[lane+64];
  bool mxa=(g3[lane]>=0.f), mxb=(g3[lane+64]>=0.f);
  __syncthreads();

  float sum0=0.f,sq0=0.f,sum1=0.f,sq1=0.f;
  float e0 = mxa? -__builtin_inff(): __builtin_inff();
  float e1 = mxb? -__builtin_inff(): __builtin_inff();
  const int rowBase = blockIdx.x*256 + wv*64;
  float* h0 = &h0L[wv][0][0];
  float* h1 = &h1L[wv][0][0];
  float* h2 = &h2L[wv][0][0];

  for(int bt=0; bt<4; ++bt){
    const int rb = rowBase + bt*16;
    h0[(lane&7)*20 + (lane>>3)]     = grouped[(size_t)rb*8 + lane];
    h0[(lane&7)*20 + 8 + (lane>>3)] = grouped[(size_t)(rb+8)*8 + lane];
    __builtin_amdgcn_wave_barrier();
    float a1A[8], a1B[8];
    #pragma unroll
    for(int r=0;r<8;r++){ a1A[r]=bias1a; a1B[r]=bias1b; }
    #pragma unroll
    for(int c=0;c<6;c++){
      float4 lo = *(const float4*)&h0[c*20+r8];
      float4 hi = *(const float4*)&h0[c*20+r8+4];
      fma8(a1A, lo, hi, w1r0[c]);
      fma8(a1B, lo, hi, w1r1[c]);
    }
    #pragma unroll
    for(int r=0;r<8;r++){
      a1A[r]=fmaxf(fmaf(a1A[r],A1a,B1a),0.f);
      a1B[r]=fmaxf(fmaf(a1B[r],A1b,B1b),0.f);
    }
    *(float4*)&h1[c0*20+r8]   = make_float4(a1A[0],a1A[1],a1A[2],a1A[3]);
    *(float4*)&h1[c0*20+r8+4] = make_float4(a1A[4],a1A[5],a1A[6],a1A[7]);
    *(float4*)&h1[c1*20+r8]   = make_float4(a1B[0],a1B[1],a1B[2],a1B[3]);
    *(float4*)&h1[c1*20+r8+4] = make_float4(a1B[4],a1B[5],a1B[6],a1B[7]);
    __builtin_amdgcn_wave_barrier();
    float a2A[8], a2B[8];
    #pragma unroll
    for(int r=0;r<8;r++){ a2A[r]=bias2a; a2B[r]=bias2b; }
    #pragma unroll
    for(int c=0;c<64;c++){
      float4 lo = *(const float4*)&h1[c*20+r8];
      float4 hi = *(const float4*)&h1[c*20+r8+4];
      float2 w = ws2[c][li];
      fma8(a2A, lo, hi, w.x);
      fma8(a2B, lo, hi, w.y);
    }
    #pragma unroll
    for(int r=0;r<8;r++){
      a2A[r]=fmaxf(fmaf(a2A[r],A2a,B2a),0.f);
      a2B[r]=fmaxf(fmaf(a2B[r],A2b,B2b),0.f);
    }
    *(float4*)&h2[c0*20+r8]   = make_float4(a2A[0],a2A[1],a2A[2],a2A[3]);
    *(float4*)&h2[c0*20+r8+4] = make_float4(a2A[4],a2A[5],a2A[6],a2A[7]);
    *(float4*)&h2[c1*20+r8]   = make_float4(a2B[0],a2B[1],a2B[2],a2B[3]);
    *(float4*)&h2[c1*20+r8+4] = make_float4(a2B[4],a2B[5],a2B[6],a2B[7]);
    __builtin_amdgcn_wave_barrier();
    #pragma unroll
    for(int s=0;s<2;s++){
      float a3a[8], a3b[8];
      #pragma unroll
      for(int r=0;r<8;r++){ a3a[r]=bias3a; a3b[r]=bias3b; }
      #pragma unroll
      for(int c=0;c<64;c++){
        float4 lo = *(const float4*)&h2[c*20+s*8];
        float4 hi = *(const float4*)&h2[c*20+s*8+4];
        fma8(a3a, lo, hi, w3a[c]);
        fma8(a3b, lo, hi, w3b[c]);
      }
      #pragma unroll
      for(int r=0;r<8;r++){
        float va=a3a[r]; sum0+=va; sq0=fmaf(va,va,sq0);
        e0 = mxa? fmaxf(e0,va): fminf(e0,va);
        float vb=a3b[r]; sum1+=vb; sq1=fmaf(vb,vb,sq1);
        e1 = mxb? fmaxf(e1,vb): fminf(e1,vb);
      }
    }
    if (bt&1){
      int gg = (rowBase>>5) + (bt>>1);
      pre3[(size_t)gg*128 + lane]      = e0;
      pre3[(size_t)gg*128 + 64 + lane] = e1;
      e0 = mxa? -__builtin_inff(): __builtin_inff();
      e1 = mxb? -__builtin_inff(): __builtin_inff();
    }
    __builtin_amdgcn_wave_barrier();
  }
  atomicAdd(&sAcc[lane],      sum0);
  atomicAdd(&sAcc[64+lane],   sum1);
  atomicAdd(&sAcc[128+lane],  sq0);
  atomicAdd(&sAcc[192+lane],  sq1);
  __syncthreads();
  for(int i=t;i<128;i+=256) atomicAdd(&stats[256+i], sAcc[i]);
  for(int i=t;i<128;i+=256) atomicAdd(&stats[384+i], sAcc[128+i]);
}

// ---------------------------------------------------------------------------
// Final: BN3 affine + relu on per-group extremes, transpose to [B,128,S]
// ---------------------------------------------------------------------------
__global__ __launch_bounds__(256) void k_final(const float* __restrict__ pre3,
                                               const float* __restrict__ stats,
                                               const float* __restrict__ g3,
                                               const float* __restrict__ bb3,
                                               float* __restrict__ outNP){
  __shared__ float A3[128], B3[128];
  __shared__ float til[128][65];
  const int t=threadIdx.x;
  if (t<128){
    float mm = stats[256+t]*INV_CNT;
    float vv = stats[384+t]*INV_CNT - mm*mm;
    float aa = g3[t]*rsqrtf(vv+BN_EPS_);
    A3[t]=aa; B3[t]=bb3[t]-mm*aa;
  }
  const int b = blockIdx.x>>4, s0=(blockIdx.x&15)*64;
  #pragma unroll
  for(int i=0;i<32;i++){
    int lin=i*256+t; int sl=lin>>7, o=lin&127;
    til[o][sl]=pre3[((size_t)b*NS + s0 + sl)*128 + o];
  }
  __syncthreads();
  #pragma unroll
  for(int i=0;i<32;i++){
    int lin=i*256+t; int o=lin>>6, sl=lin&63;
    outNP[(size_t)b*128*NS + (size_t)o*NS + s0 + sl] =
        fmaxf(fmaf(til[o][sl],A3[o],B3[o]),0.f);
  }
}

extern "C" void kernel_launch(void* const* d_in, const int* in_sizes, int n_in,
                              void* d_out, int out_size, void* d_ws, size_t ws_size,
                              hipStream_t stream){
  const float* xyz=(const float*)d_in[0];
  const float* pts=(const float*)d_in[1];
  const float* w1 =(const float*)d_in[2];
  const float* b1 =(const float*)d_in[3];
  const float* g1 =(const float*)d_in[4];
  const float* bb1=(const float*)d_in[5];
  const float* w2 =(const float*)d_in[6];
  const float* b2 =(const float*)d_in[7];
  const float* g2 =(const float*)d_in[8];
  const float* bb2=(const float*)d_in[9];
  const float* w3 =(const float*)d_in[10];
  const float* b3 =(const float*)d_in[11];
  const float* g3 =(const float*)d_in[12];
  const float* bb3=(const float*)d_in[13];
  float* out=(float*)d_out;
  float* outNewXyz=out;
  float* outNP=out + (size_t)NB*3*NS;

  char* ws=(char*)d_ws;
  const size_t BASE = 4096 + 65536 + 262144 + 16777216 + 2097152; // ~19.2MB
  float* stats  =(float*)ws;                                   // 512 floats
  int*   fpsIdx =(int*)  (ws + 4096);                          // 16K ints
  float* norms  =(float*)(ws + 4096 + 65536);                  // 64K floats
  float* grouped=(float*)(ws + 4096 + 65536 + 262144);         // 4M floats
  float* pre3   =(float*)(ws + 4096 + 65536 + 262144 + 16777216); // 2M floats
  float* h2raw  =(float*)(ws + BASE);                          // 33.5M floats (134MB)
  const bool split = ws_size >= BASE + 134217728ull;

  k_fps  <<<dim3(NB),       dim3(256),  0, stream>>>(xyz, fpsIdx, norms, outNewXyz, stats);
  k_group<<<dim3(NB*NS/4),  dim3(256),  0, stream>>>(xyz, pts, norms, fpsIdx, grouped);
  k_mlp1 <<<dim3(2048), dim3(256), 0, stream>>>(grouped, w1,b1, stats);
  if (split){
    k_mlp2<1><<<dim3(2048), dim3(256), 0, stream>>>(grouped, w1,b1,w2,b2, g1,bb1, stats, h2raw);
    k_mlp3b  <<<dim3(2048), dim3(256), 0, stream>>>(h2raw, w3,b3, g2,bb2, g3, stats, pre3);
  } else {
    k_mlp2<0><<<dim3(2048), dim3(256), 0, stream>>>(grouped, w1,b1,w2,b2, g1,bb1, stats, h2raw);
    k_mlp3   <<<dim3(2048), dim3(256), 0, stream>>>(grouped, w1,b1,w2,b2,w3,b3, g1,bb1,g2,bb2,g3, stats, pre3);
  }
  k_final<<<dim3(256),  dim3(256), 0, stream>>>(pre3, stats, g3, bb3, outNP);
}